// Round 2
// baseline (158.930 us; speedup 1.0000x reference)
//
#include <hip/hip_runtime.h>
#include <hip/hip_bf16.h>
#include <stdint.h>

// Problem geometry
#define B_   64
#define C_   512
#define L_   784      // 28*28
#define LP   800      // padded row length (25 * 32), pad is zero-filled
#define TILE 128
#define NT   4        // C_/TILE
#define NBLK_PER_B 36 // 10 (tt upper) + 10 (ss upper) + 16 (st full)

#define AS1 __attribute__((address_space(1)))
#define AS3 __attribute__((address_space(3)))

typedef __attribute__((ext_vector_type(8))) __bf16 bf16x8;
typedef __attribute__((ext_vector_type(4))) float  f32x4;

// ---------------------------------------------------------------------------
// round-to-nearest-even float -> bf16 bits (data has no NaN/Inf)
__device__ inline unsigned short f2bf(float x) {
    union { float f; uint32_t u; } a; a.f = x;
    uint32_t u = a.u;
    return (unsigned short)((u + 0x7fffu + ((u >> 16) & 1u)) >> 16);
}

// ---------------------------------------------------------------------------
// Pass 0: zero the partial-sum accumulators (ws is poisoned by harness)
__global__ void init_kernel(float* partials) {
    if (threadIdx.x < 16) partials[threadIdx.x] = 0.0f;
}

// ---------------------------------------------------------------------------
// Pass 1: L2-normalize each [784] row (fp32), write bf16 padded to LP=800.
// One wave per row; 4 waves (256 threads) per block.
__global__ __launch_bounds__(256) void normalize_kernel(
    const float* __restrict__ fs, const float* __restrict__ ft,
    unsigned short* __restrict__ outT, unsigned short* __restrict__ outS)
{
    int gwave = blockIdx.x * 4 + (threadIdx.x >> 6);
    int lane  = threadIdx.x & 63;
    int mat   = gwave >> 15;          // 0 -> t, 1 -> s  (32768 rows each)
    int row   = gwave & 32767;

    const float* src = (mat == 0 ? ft : fs) + (size_t)row * L_;
    unsigned short* dst = (mat == 0 ? outT : outS) + (size_t)row * LP;

    float4 v[4];
    float ss = 0.0f;
#pragma unroll
    for (int it = 0; it < 4; ++it) {
        int c = it * 64 + lane;       // float4 chunk index, 196 chunks/row
        if (c < 196) {
            v[it] = reinterpret_cast<const float4*>(src)[c];
            ss += v[it].x * v[it].x + v[it].y * v[it].y
                + v[it].z * v[it].z + v[it].w * v[it].w;
        }
    }
#pragma unroll
    for (int m = 32; m >= 1; m >>= 1) ss += __shfl_xor(ss, m, 64);
    float rn = 1.0f / fmaxf(sqrtf(ss), 1e-12f);

#pragma unroll
    for (int it = 0; it < 4; ++it) {
        int c = it * 64 + lane;
        if (c < 196) {
            ushort4 o;
            o.x = f2bf(v[it].x * rn);
            o.y = f2bf(v[it].y * rn);
            o.z = f2bf(v[it].z * rn);
            o.w = f2bf(v[it].w * rn);
            *reinterpret_cast<ushort4*>(dst + (size_t)c * 4) = o;
        } else if (c < 200) {         // zero the 16-element pad (784..799)
            *reinterpret_cast<ushort4*>(dst + (size_t)c * 4) = make_ushort4(0, 0, 0, 0);
        }
    }
}

// ---------------------------------------------------------------------------
// Pass 2: per (batch, gram, tile) block computes a 128x128x800 GEMM tile of
// G = X_rows . Y_rows^T and accumulates weight * sum(G^2) into partials[gram].
// 256 threads = 4 waves in a 2x2 grid of 64x64 sub-tiles; mfma 16x16x32 bf16.
__global__ __launch_bounds__(256) void gram_kernel(
    const unsigned short* __restrict__ Tn,
    const unsigned short* __restrict__ Sn,
    float* __restrict__ partials)
{
    int blk = blockIdx.x;
    int b   = blk / NBLK_PER_B;
    int t   = blk % NBLK_PER_B;

    int g, ti, tj;
    if (t < 20) {
        g = t / 10;                    // 0: t.t^T, 1: s.s^T
        int u = t % 10;                // upper-triangle enumeration of 4x4
        if      (u < 4) { ti = 0; tj = u;     }
        else if (u < 7) { ti = 1; tj = u - 3; }
        else if (u < 9) { ti = 2; tj = u - 5; }
        else            { ti = 3; tj = 3;     }
    } else {
        g = 2;                         // t.s^T (full)
        int u = t - 20;
        ti = u >> 2; tj = u & 3;
    }
    float w = (g < 2 && ti != tj) ? 2.0f : 1.0f;

    const unsigned short* X = (g == 0 ? Tn : Sn) + (size_t)b * C_ * LP + (size_t)ti * TILE * LP;
    const unsigned short* Y = (g == 1 ? Sn : Tn) + (size_t)b * C_ * LP + (size_t)tj * TILE * LP;

    __shared__ unsigned short lA[TILE * 32];
    __shared__ unsigned short lB[TILE * 32];
    __shared__ float red[4];

    int tid  = threadIdx.x;
    int wid  = tid >> 6;
    int lane = tid & 63;
    int wr   = wid >> 1, wc = wid & 1;

    int arow = wr * 64 + (lane & 15);
    int brow = wc * 64 + (lane & 15);
    int koff = (lane >> 4) * 8;

    f32x4 acc[4][4] = {};

    for (int kk = 0; kk < 25; ++kk) {
        int k0 = kk * 32;
        // ---- stage A,B tiles (128x32 bf16 each) via global_load_lds x16B ----
#pragma unroll
        for (int p = 0; p < 2; ++p) {
            int c  = p * 256 + tid;            // 16B-chunk id, 0..511
            int r  = c >> 2;                   // tile row
            int cc = c & 3;                    // 8-elem chunk within row
            const unsigned short* ga = X + (size_t)r * LP + k0 + cc * 8;
            const unsigned short* gb = Y + (size_t)r * LP + k0 + cc * 8;
            unsigned short* la = &lA[(size_t)(p * 256 + wid * 64) * 8];  // wave-uniform
            unsigned short* lb = &lB[(size_t)(p * 256 + wid * 64) * 8];
            __builtin_amdgcn_global_load_lds((AS1 const void*)ga, (AS3 void*)la, 16, 0, 0);
            __builtin_amdgcn_global_load_lds((AS1 const void*)gb, (AS3 void*)lb, 16, 0, 0);
        }
        __syncthreads();

        bf16x8 af[4], bfr[4];
#pragma unroll
        for (int m = 0; m < 4; ++m)
            af[m] = *reinterpret_cast<const bf16x8*>(&lA[(size_t)(arow + m * 16) * 32 + koff]);
#pragma unroll
        for (int n = 0; n < 4; ++n)
            bfr[n] = *reinterpret_cast<const bf16x8*>(&lB[(size_t)(brow + n * 16) * 32 + koff]);

#pragma unroll
        for (int m = 0; m < 4; ++m)
#pragma unroll
            for (int n = 0; n < 4; ++n)
                acc[m][n] = __builtin_amdgcn_mfma_f32_16x16x32_bf16(af[m], bfr[n], acc[m][n], 0, 0, 0);
        __syncthreads();
    }

    // ---- epilogue: sum of squares over the whole tile (layout-free) ----
    float local = 0.0f;
#pragma unroll
    for (int m = 0; m < 4; ++m)
#pragma unroll
        for (int n = 0; n < 4; ++n)
#pragma unroll
            for (int j = 0; j < 4; ++j) {
                float x = acc[m][n][j];
                local += x * x;
            }
#pragma unroll
    for (int m = 32; m >= 1; m >>= 1) local += __shfl_xor(local, m, 64);
    if (lane == 0) red[wid] = local;
    __syncthreads();
    if (tid == 0) {
        float tot = (red[0] + red[1] + red[2] + red[3]) * w;
        atomicAdd(&partials[g], tot);
    }
}

// ---------------------------------------------------------------------------
__global__ void finalize_kernel(const float* __restrict__ partials, float* __restrict__ out) {
    // mean over B*C*C = 64*512*512 = 16777216
    out[0] = (partials[0] + partials[1] - 2.0f * partials[2]) * (1.0f / 16777216.0f);
}

// ---------------------------------------------------------------------------
extern "C" void kernel_launch(void* const* d_in, const int* in_sizes, int n_in,
                              void* d_out, int out_size, void* d_ws, size_t ws_size,
                              hipStream_t stream) {
    const float* fs = (const float*)d_in[0];   // fm_s
    const float* ft = (const float*)d_in[1];   // fm_t
    float* out = (float*)d_out;

    char* ws = (char*)d_ws;
    float* partials = (float*)ws;                                  // 64 B
    unsigned short* Tn = (unsigned short*)(ws + 256);
    unsigned short* Sn = (unsigned short*)(ws + 256 + (size_t)B_ * C_ * LP * 2);
    // total ws use: 256 + 2*64*512*800*2 = ~104.9 MB

    hipLaunchKernelGGL(init_kernel, dim3(1), dim3(64), 0, stream, partials);
    hipLaunchKernelGGL(normalize_kernel, dim3((2 * B_ * C_) / 4), dim3(256), 0, stream,
                       fs, ft, Tn, Sn);
    hipLaunchKernelGGL(gram_kernel, dim3(B_ * NBLK_PER_B), dim3(256), 0, stream,
                       Tn, Sn, partials);
    hipLaunchKernelGGL(finalize_kernel, dim3(1), dim3(1), 0, stream, partials, out);
}

// Round 3
// 157.759 us; speedup vs baseline: 1.0074x; 1.0074x over previous
//
#include <hip/hip_runtime.h>
#include <hip/hip_bf16.h>
#include <stdint.h>

// Problem geometry
#define B_   64
#define C_   512
#define L_   784      // 28*28
#define LP   800      // padded row length (25 * 32), pad is zero-filled
#define TILE 128
#define NBLK_PER_B 36 // 10 (tt upper) + 10 (ss upper) + 16 (st full)
#define KSTEPS 25

#define AS1 __attribute__((address_space(1)))
#define AS3 __attribute__((address_space(3)))

typedef __attribute__((ext_vector_type(8))) __bf16 bf16x8;
typedef __attribute__((ext_vector_type(4))) float  f32x4;

#define WAITV4 asm volatile("s_waitcnt vmcnt(4)" ::: "memory")
#define WAITV0 asm volatile("s_waitcnt vmcnt(0)" ::: "memory")
#define SBAR   __builtin_amdgcn_s_barrier()
#define SCHED0 __builtin_amdgcn_sched_barrier(0)

// ---------------------------------------------------------------------------
// round-to-nearest-even float -> bf16 bits (data has no NaN/Inf)
__device__ inline unsigned short f2bf(float x) {
    union { float f; uint32_t u; } a; a.f = x;
    uint32_t u = a.u;
    return (unsigned short)((u + 0x7fffu + ((u >> 16) & 1u)) >> 16);
}

// ---------------------------------------------------------------------------
__global__ void init_kernel(float* partials) {
    if (threadIdx.x < 16) partials[threadIdx.x] = 0.0f;
}

// ---------------------------------------------------------------------------
// Pass 1: L2-normalize each [784] row (fp32), write bf16 padded to LP=800.
// One wave per row; 4 waves (256 threads) per block.  ~BW-bound already.
__global__ __launch_bounds__(256) void normalize_kernel(
    const float* __restrict__ fs, const float* __restrict__ ft,
    unsigned short* __restrict__ outT, unsigned short* __restrict__ outS)
{
    int gwave = blockIdx.x * 4 + (threadIdx.x >> 6);
    int lane  = threadIdx.x & 63;
    int mat   = gwave >> 15;          // 0 -> t, 1 -> s  (32768 rows each)
    int row   = gwave & 32767;

    const float* src = (mat == 0 ? ft : fs) + (size_t)row * L_;
    unsigned short* dst = (mat == 0 ? outT : outS) + (size_t)row * LP;

    float4 v[4];
    float ss = 0.0f;
#pragma unroll
    for (int it = 0; it < 4; ++it) {
        int c = it * 64 + lane;       // float4 chunk index, 196 chunks/row
        if (c < 196) {
            v[it] = reinterpret_cast<const float4*>(src)[c];
            ss += v[it].x * v[it].x + v[it].y * v[it].y
                + v[it].z * v[it].z + v[it].w * v[it].w;
        }
    }
#pragma unroll
    for (int m = 32; m >= 1; m >>= 1) ss += __shfl_xor(ss, m, 64);
    float rn = 1.0f / fmaxf(sqrtf(ss), 1e-12f);

#pragma unroll
    for (int it = 0; it < 4; ++it) {
        int c = it * 64 + lane;
        if (c < 196) {
            ushort4 o;
            o.x = f2bf(v[it].x * rn);
            o.y = f2bf(v[it].y * rn);
            o.z = f2bf(v[it].z * rn);
            o.w = f2bf(v[it].w * rn);
            *reinterpret_cast<ushort4*>(dst + (size_t)c * 4) = o;
        } else if (c < 200) {         // zero the 16-element pad (784..799)
            *reinterpret_cast<ushort4*>(dst + (size_t)c * 4) = make_ushort4(0, 0, 0, 0);
        }
    }
}

// ---------------------------------------------------------------------------
// Stage one K-step's A,B tiles (128x32 bf16 each) into LDS buffer `base`
// (A at base, B at base+4096 shorts) via global_load_lds width=16.
// Dest is wave-uniform base + lane*16B, as HW requires.
__device__ __forceinline__ void stage_tiles(
    const unsigned short* __restrict__ X, const unsigned short* __restrict__ Y,
    int k0, unsigned short* base, int tid, int wid)
{
#pragma unroll
    for (int p = 0; p < 2; ++p) {
        int c  = p * 256 + tid;            // 16B-chunk id, 0..511
        int r  = c >> 2;                   // tile row
        int cc = c & 3;                    // 8-elem chunk within row
        const unsigned short* ga = X + (size_t)r * LP + k0 + cc * 8;
        const unsigned short* gb = Y + (size_t)r * LP + k0 + cc * 8;
        unsigned short* la = base + (size_t)(p * 256 + wid * 64) * 8;
        unsigned short* lb = base + 4096 + (size_t)(p * 256 + wid * 64) * 8;
        __builtin_amdgcn_global_load_lds((AS1 const void*)ga, (AS3 void*)la, 16, 0, 0);
        __builtin_amdgcn_global_load_lds((AS1 const void*)gb, (AS3 void*)lb, 16, 0, 0);
    }
}

// ---------------------------------------------------------------------------
// Pass 2: per (batch, gram, tile) block computes a 128x128x800 GEMM tile of
// G = X_rows . Y_rows^T and accumulates weight * sum(G^2) into partials[gram].
// 4 waves in 2x2 grid of 64x64 sub-tiles; mfma 16x16x32 bf16.
// Triple-buffered LDS, depth-2 prefetch, counted vmcnt(4), raw barriers.
__global__ __launch_bounds__(256) void gram_kernel(
    const unsigned short* __restrict__ Tn,
    const unsigned short* __restrict__ Sn,
    float* __restrict__ partials)
{
    int blk = blockIdx.x;
    int b   = blk / NBLK_PER_B;
    int t   = blk % NBLK_PER_B;

    int g, ti, tj;
    if (t < 20) {
        g = t / 10;                    // 0: t.t^T, 1: s.s^T
        int u = t % 10;                // upper-triangle enumeration of 4x4
        if      (u < 4) { ti = 0; tj = u;     }
        else if (u < 7) { ti = 1; tj = u - 3; }
        else if (u < 9) { ti = 2; tj = u - 5; }
        else            { ti = 3; tj = 3;     }
    } else {
        g = 2;                         // t.s^T (full)
        int u = t - 20;
        ti = u >> 2; tj = u & 3;
    }
    float w = (g < 2 && ti != tj) ? 2.0f : 1.0f;

    const unsigned short* X = (g == 0 ? Tn : Sn) + (size_t)b * C_ * LP + (size_t)ti * TILE * LP;
    const unsigned short* Y = (g == 1 ? Sn : Tn) + (size_t)b * C_ * LP + (size_t)tj * TILE * LP;

    // 3 buffers x (A 8KB + B 8KB) = 48 KiB
    __shared__ unsigned short lds[3 * 8192];
    __shared__ float red[4];

    int tid  = threadIdx.x;
    int wid  = tid >> 6;
    int lane = tid & 63;
    int wr   = wid >> 1, wc = wid & 1;

    int arow = wr * 64 + (lane & 15);
    int brow = wc * 64 + (lane & 15);
    int koff = (lane >> 4) * 8;

    f32x4 acc[4][4] = {};

    unsigned short* cur = lds;
    unsigned short* nx1 = lds + 8192;
    unsigned short* nx2 = lds + 16384;

    // prologue: prefetch tiles 0 and 1 (8 loads/thread outstanding)
    stage_tiles(X, Y, 0,  cur, tid, wid);
    stage_tiles(X, Y, 32, nx1, tid, wid);
    WAITV4;                 // tile 0 complete (newest 4 still in flight)
    SBAR; SCHED0;

#define COMPUTE_STEP(BUF)                                                           \
    {                                                                               \
        bf16x8 af[4], bfr[4];                                                       \
        _Pragma("unroll")                                                           \
        for (int m = 0; m < 4; ++m)                                                 \
            af[m] = *reinterpret_cast<const bf16x8*>((BUF) + (size_t)(arow + m * 16) * 32 + koff); \
        _Pragma("unroll")                                                           \
        for (int n = 0; n < 4; ++n)                                                 \
            bfr[n] = *reinterpret_cast<const bf16x8*>((BUF) + 4096 + (size_t)(brow + n * 16) * 32 + koff); \
        _Pragma("unroll")                                                           \
        for (int m = 0; m < 4; ++m)                                                 \
            _Pragma("unroll")                                                       \
            for (int n = 0; n < 4; ++n)                                             \
                acc[m][n] = __builtin_amdgcn_mfma_f32_16x16x32_bf16(af[m], bfr[n], acc[m][n], 0, 0, 0); \
    }

    // main loop: t = 0..22, stage t+2, compute t, wait tile t+1 (vmcnt(4))
    for (int kt = 0; kt < KSTEPS - 2; ++kt) {
        stage_tiles(X, Y, (kt + 2) * 32, nx2, tid, wid);
        COMPUTE_STEP(cur);
        WAITV4;             // tile kt+1 ready; tile kt+2's 4 loads in flight
        SBAR; SCHED0;
        unsigned short* tmp = cur; cur = nx1; nx1 = nx2; nx2 = tmp;
    }
    // kt = 23: no stage; wait last tile fully
    COMPUTE_STEP(cur);
    WAITV0;                 // tile 24 ready
    SBAR; SCHED0;
    { unsigned short* tmp = cur; cur = nx1; nx1 = nx2; nx2 = tmp; }
    // kt = 24: final compute, no trailing sync needed
    COMPUTE_STEP(cur);

    // ---- epilogue: sum of squares over the whole tile (layout-free) ----
    float local = 0.0f;
#pragma unroll
    for (int m = 0; m < 4; ++m)
#pragma unroll
        for (int n = 0; n < 4; ++n)
#pragma unroll
            for (int j = 0; j < 4; ++j) {
                float x = acc[m][n][j];
                local += x * x;
            }
#pragma unroll
    for (int m = 32; m >= 1; m >>= 1) local += __shfl_xor(local, m, 64);
    if (lane == 0) red[wid] = local;
    __syncthreads();
    if (tid == 0) {
        float tot = (red[0] + red[1] + red[2] + red[3]) * w;
        atomicAdd(&partials[g], tot);
    }
}

// ---------------------------------------------------------------------------
__global__ void finalize_kernel(const float* __restrict__ partials, float* __restrict__ out) {
    // mean over B*C*C = 64*512*512 = 16777216
    out[0] = (partials[0] + partials[1] - 2.0f * partials[2]) * (1.0f / 16777216.0f);
}

// ---------------------------------------------------------------------------
extern "C" void kernel_launch(void* const* d_in, const int* in_sizes, int n_in,
                              void* d_out, int out_size, void* d_ws, size_t ws_size,
                              hipStream_t stream) {
    const float* fs = (const float*)d_in[0];   // fm_s
    const float* ft = (const float*)d_in[1];   // fm_t
    float* out = (float*)d_out;

    char* ws = (char*)d_ws;
    float* partials = (float*)ws;                                  // 64 B
    unsigned short* Tn = (unsigned short*)(ws + 256);
    unsigned short* Sn = (unsigned short*)(ws + 256 + (size_t)B_ * C_ * LP * 2);
    // total ws use: 256 + 2*64*512*800*2 = ~104.9 MB

    hipLaunchKernelGGL(init_kernel, dim3(1), dim3(64), 0, stream, partials);
    hipLaunchKernelGGL(normalize_kernel, dim3((2 * B_ * C_) / 4), dim3(256), 0, stream,
                       fs, ft, Tn, Sn);
    hipLaunchKernelGGL(gram_kernel, dim3(B_ * NBLK_PER_B), dim3(256), 0, stream,
                       Tn, Sn, partials);
    hipLaunchKernelGGL(finalize_kernel, dim3(1), dim3(1), 0, stream, partials, out);
}